// Round 8
// baseline (139.754 us; speedup 1.0000x reference)
//
#include <hip/hip_runtime.h>
#include <hip/hip_bf16.h>

#define Bsz 16
#define Nn  1024
#define Ff  256
#define ALPHA 0.2f
#define NEG_BIG -9.0e15f

typedef __attribute__((ext_vector_type(8))) short short8;
typedef __attribute__((ext_vector_type(4))) float f32x4;
typedef __attribute__((ext_vector_type(4))) unsigned short ushort4_t;

__device__ __forceinline__ unsigned short f2bf(float x) {
    union { __hip_bfloat16 b; unsigned short u; } cv;
    cv.b = __float2bfloat16(x);
    return cv.u;
}

// ---- K0: blocks 0..63: w1 = W@a1, w2 = W@a2 ; blocks 64..71: pack WK ------
__global__ __launch_bounds__(256) void gat_prep(
    const float* __restrict__ W, const float* __restrict__ a,
    float* __restrict__ w1, float* __restrict__ w2,
    unsigned short* __restrict__ WK)
{
    const int t = threadIdx.x, w = t >> 6, ln = t & 63;
    if (blockIdx.x < 64) {
        __shared__ float a1s[Ff], a2s[Ff];
        a1s[t] = a[t];
        a2s[t] = a[Ff + t];
        __syncthreads();
        const int f = blockIdx.x * 4 + w;
        float s1 = 0.f, s2 = 0.f;
        #pragma unroll
        for (int c = 0; c < 4; c++) {
            const int o = ln + 64 * c;
            const float wv = W[(size_t)f * Ff + o];
            s1 += wv * a1s[o];
            s2 += wv * a2s[o];
        }
        #pragma unroll
        for (int off = 1; off < 64; off <<= 1) {
            s1 += __shfl_xor(s1, off, 64);
            s2 += __shfl_xor(s2, off, 64);
        }
        if (ln == 0) { w1[f] = s1; w2[f] = s2; }
        return;
    }
    // WK pack (K-tile layout: ushort idx o*32+kk = W[kt*32+kk][o]) — verbatim
    // from the r7 pack_f W branch (same layout its phase-C consumer used).
    __shared__ __align__(16) float tile[32][258];
    const int ft = blockIdx.x - 64;
    const float* src = W + (size_t)ft * 32 * Ff;
    #pragma unroll
    for (int rr = 0; rr < 8; rr++) {
        const int row = rr * 4 + w;
        const int col = ln * 4;
        const float4 v = *(const float4*)&src[row * Ff + col];
        float2* tr = (float2*)&tile[row][col];
        tr[0] = make_float2(v.x, v.y);
        tr[1] = make_float2(v.z, v.w);
    }
    __syncthreads();
    unsigned* d32 = (unsigned*)(WK + (size_t)ft * 8192);
    #pragma unroll
    for (int k = 0; k < 16; k++) {
        const int fidx = k * 256 + t;
        const int o = fidx >> 4, q = fidx & 15;
        const unsigned lo = f2bf(tile[2 * q][o]);
        const unsigned hi = f2bf(tile[2 * q + 1][o]);
        d32[fidx] = lo | (hi << 16);
    }
}

// ---- K1: stage h-tile -> f1/f2 + Wh = h@W (MFMA) -> WhK packed ------------
// Associativity: attn needs (P@h)@W = P@(h@W). Computing Wh here (h-tile is
// already in LDS; B-operand = WK in the exact phase-C fragment layout)
// deletes attn's entire phase C + G round-trip + 2 barriers.
__global__ __launch_bounds__(256) void pack_f(
    const float* __restrict__ h, const unsigned short* __restrict__ WK,
    const float* __restrict__ w1, const float* __restrict__ w2,
    unsigned short* __restrict__ WhK,
    float* __restrict__ f1, float* __restrict__ f2)
{
    __shared__ __align__(16) float tile[32][258];
    const int id = blockIdx.x, t = threadIdx.x, w = t >> 6, ln = t & 63;
    const int grow0 = id * 32;                 // rows id*32 .. +31
    const float* src = h + (size_t)grow0 * Ff;
    #pragma unroll
    for (int rr = 0; rr < 8; rr++) {
        const int row = rr * 4 + w;
        const int col = ln * 4;
        const float4 v = *(const float4*)&src[row * Ff + col];
        float2* tr = (float2*)&tile[row][col];
        tr[0] = make_float2(v.x, v.y);
        tr[1] = make_float2(v.z, v.w);
    }
    __syncthreads();

    // f1/f2 from fp32 h (r7-proven path, keeps absmax at 0.0156)
    {
        float w1r[4], w2r[4];
        #pragma unroll
        for (int c = 0; c < 4; c++) {
            w1r[c] = w1[ln + 64 * c];
            w2r[c] = w2[ln + 64 * c];
        }
        #pragma unroll
        for (int rr = 0; rr < 8; rr++) {
            const int row = rr * 4 + w;
            float s1 = 0.f, s2 = 0.f;
            #pragma unroll
            for (int c = 0; c < 4; c++) {
                const float hv = tile[row][ln + 64 * c];
                s1 += hv * w1r[c];
                s2 += hv * w2r[c];
            }
            #pragma unroll
            for (int off = 1; off < 64; off <<= 1) {
                s1 += __shfl_xor(s1, off, 64);
                s2 += __shfl_xor(s2, off, 64);
            }
            if (ln == 0) { f1[grow0 + row] = s1; f2[grow0 + row] = s2; }
        }
    }

    // GEMM: Wh-tile (32 nodes x 256 feats). Wave w owns feats w*64..+63
    // (4 n-tiles) x both 16-node m-halves. A from LDS (cvt f32->bf16),
    // B from WK (L2-resident, phase-C WB pattern).
    const int m = ln & 15, quad = ln >> 4;
    f32x4 acc0[4], acc1[4];
    #pragma unroll
    for (int nt = 0; nt < 4; nt++) {
        f32x4 z = {0.f, 0.f, 0.f, 0.f};
        acc0[nt] = z; acc1[nt] = z;
    }
    #pragma unroll
    for (int kt = 0; kt < 8; kt++) {
        short8 a0, a1;
        {
            const float* p0 = &tile[m][kt * 32 + quad * 8];
            const float* p1 = &tile[16 + m][kt * 32 + quad * 8];
            #pragma unroll
            for (int e = 0; e < 8; e++) {
                a0[e] = (short)f2bf(p0[e]);
                a1[e] = (short)f2bf(p1[e]);
            }
        }
        #pragma unroll
        for (int nt = 0; nt < 4; nt++) {
            const short8 bfr = *(const short8*)&WK[(size_t)kt * 8192 + (w * 64 + nt * 16 + m) * 32 + quad * 8];
            acc0[nt] = __builtin_amdgcn_mfma_f32_16x16x32_bf16(a0, bfr, acc0[nt], 0, 0, 0);
            acc1[nt] = __builtin_amdgcn_mfma_f32_16x16x32_bf16(a1, bfr, acc1[nt], 0, 0, 0);
        }
    }
    // WhK pack: ushort idx o*32 + node (same K-tile layout as hK had)
    unsigned short* dst = WhK + (size_t)id * 8192;
    #pragma unroll
    for (int nt = 0; nt < 4; nt++) {
        const int o = w * 64 + nt * 16 + m;
        ushort4_t v0 = { f2bf(acc0[nt][0]), f2bf(acc0[nt][1]),
                         f2bf(acc0[nt][2]), f2bf(acc0[nt][3]) };
        ushort4_t v1 = { f2bf(acc1[nt][0]), f2bf(acc1[nt][1]),
                         f2bf(acc1[nt][2]), f2bf(acc1[nt][3]) };
        *(ushort4_t*)&dst[o * 32 + quad * 4]      = v0;
        *(ushort4_t*)&dst[o * 32 + 16 + quad * 4] = v1;
    }
}

// ---- K2: softmax -> out = elu( P @ Wh ) (single MFMA phase, ONE barrier) --
// P LDS stride 1040 ushorts (2080 B, != 0 mod 128B): row shift spreads the
// m-lanes across bank groups; with the XOR swizzle the AF b128 reads drop
// from ~8-way to <=2-way conflicts (r7: SQ_LDS_BANK_CONFLICT 2.6M).
#define TI 32
#define PST 1040
__global__ __launch_bounds__(1024, 8) void gat_attn(
    const int* __restrict__ adj,
    const float* __restrict__ f1, const float* __restrict__ f2,
    const unsigned short* __restrict__ WhK,
    float* __restrict__ out)
{
    __shared__ __align__(16) unsigned short pbf[TI * PST];   // 66,560 B
    const int t = threadIdx.x, w = t >> 6, ln = t & 63;      // 16 waves
    const int m = ln & 15, quad = ln >> 4;
    const int bid = blockIdx.x;
    const int b  = 2 * (bid & 7) + ((bid >> 3) & 1);         // XCD-local batches
    const int i0 = (bid >> 4) * TI;

    // ---- Phase A: wave w owns rows 2w, 2w+1 (r7-proven two-pass softmax) ----
    const int r0 = 2 * w, r1 = r0 + 1;
    const int grb = b * Nn + i0 + r0;
    const int* aptr = adj + (size_t)grb * Nn;
    int4 av0[4], av1[4];
    #pragma unroll
    for (int c = 0; c < 4; c++) {
        av0[c] = *(const int4*)&aptr[c * 256 + 4 * ln];
        av1[c] = *(const int4*)&aptr[Nn + c * 256 + 4 * ln];
    }
    float4 f2r[4];
    #pragma unroll
    for (int c = 0; c < 4; c++)
        f2r[c] = *(const float4*)&f2[b * Nn + 256 * c + 4 * ln];

    const float fi0 = f1[grb], fi1 = f1[grb + 1];
    float e0[16], e1[16];
    float mx0 = -INFINITY, mx1 = -INFINITY;
    #pragma unroll
    for (int c = 0; c < 4; c++) {
        const float4 fv = f2r[c];
        float x, y;
        x = fi0 + fv.x; x = fmaxf(x, ALPHA * x); x = av0[c].x > 0 ? x : NEG_BIG; e0[4*c+0] = x;
        y = fi0 + fv.y; y = fmaxf(y, ALPHA * y); y = av0[c].y > 0 ? y : NEG_BIG; e0[4*c+1] = y;
        mx0 = fmaxf(fmaxf(x, y), mx0);
        x = fi0 + fv.z; x = fmaxf(x, ALPHA * x); x = av0[c].z > 0 ? x : NEG_BIG; e0[4*c+2] = x;
        y = fi0 + fv.w; y = fmaxf(y, ALPHA * y); y = av0[c].w > 0 ? y : NEG_BIG; e0[4*c+3] = y;
        mx0 = fmaxf(fmaxf(x, y), mx0);
        x = fi1 + fv.x; x = fmaxf(x, ALPHA * x); x = av1[c].x > 0 ? x : NEG_BIG; e1[4*c+0] = x;
        y = fi1 + fv.y; y = fmaxf(y, ALPHA * y); y = av1[c].y > 0 ? y : NEG_BIG; e1[4*c+1] = y;
        mx1 = fmaxf(fmaxf(x, y), mx1);
        x = fi1 + fv.z; x = fmaxf(x, ALPHA * x); x = av1[c].z > 0 ? x : NEG_BIG; e1[4*c+2] = x;
        y = fi1 + fv.w; y = fmaxf(y, ALPHA * y); y = av1[c].w > 0 ? y : NEG_BIG; e1[4*c+3] = y;
        mx1 = fmaxf(fmaxf(x, y), mx1);
    }
    #pragma unroll
    for (int off = 1; off < 64; off <<= 1) {
        mx0 = fmaxf(mx0, __shfl_xor(mx0, off, 64));
        mx1 = fmaxf(mx1, __shfl_xor(mx1, off, 64));
    }
    float s0 = 0.f, s1 = 0.f;
    #pragma unroll
    for (int c = 0; c < 16; c++) {
        e0[c] = __expf(e0[c] - mx0); s0 += e0[c];   // all-masked row -> uniform
        e1[c] = __expf(e1[c] - mx1); s1 += e1[c];
    }
    #pragma unroll
    for (int off = 1; off < 64; off <<= 1) {
        s0 += __shfl_xor(s0, off, 64);
        s1 += __shfl_xor(s1, off, 64);
    }
    const float ri0 = 1.f / s0, ri1 = 1.f / s1;
    const int sw0 = (r0 & 7) << 3, sw1 = (r1 & 7) << 3;
    #pragma unroll
    for (int c = 0; c < 4; c++) {
        const int j = 256 * c + 4 * ln;
        ushort4_t v0 = { f2bf(e0[4*c] * ri0), f2bf(e0[4*c+1] * ri0),
                         f2bf(e0[4*c+2] * ri0), f2bf(e0[4*c+3] * ri0) };
        ushort4_t v1 = { f2bf(e1[4*c] * ri1), f2bf(e1[4*c+1] * ri1),
                         f2bf(e1[4*c+2] * ri1), f2bf(e1[4*c+3] * ri1) };
        *(ushort4_t*)&pbf[r0 * PST + (j ^ sw0)] = v0;
        *(ushort4_t*)&pbf[r1 * PST + (j ^ sw1)] = v1;
    }

    // ---- Phase B: out = elu( P @ Wh_b ) ; wave n-slice 16, both m-halves ----
    const int n0 = w * 16;
    const unsigned short* hKb = WhK + (size_t)b * 32 * 8192;
    const int arow0 = m * PST, arow1 = (16 + m) * PST;
    const int asw = (m & 7) << 3;
    #define AF0(kt) (*(const short8*)&pbf[arow0 + ((((kt) * 32) + quad * 8) ^ asw)])
    #define AF1(kt) (*(const short8*)&pbf[arow1 + ((((kt) * 32) + quad * 8) ^ asw)])
    #define BF(kt)  (*(const short8*)&hKb[(size_t)(kt) * 8192 + (n0 + m) * 32 + quad * 8])

    // 4-deep global prefetch, no pbf dependency -> issue BEFORE the barrier
    short8 bq0 = BF(0), bq1 = BF(1), bq2 = BF(2), bq3 = BF(3);
    __syncthreads();

    f32x4 acc0 = {0.f, 0.f, 0.f, 0.f}, acc1 = acc0;
    short8 a0c = AF0(0), a1c = AF1(0);
    __builtin_amdgcn_s_setprio(1);
    #pragma unroll
    for (int kt = 0; kt < 32; kt++) {
        short8 bnew = bq0, a0n = a0c, a1n = a1c;
        if (kt + 4 < 32) bnew = BF(kt + 4);
        if (kt + 1 < 32) { a0n = AF0(kt + 1); a1n = AF1(kt + 1); }
        acc0 = __builtin_amdgcn_mfma_f32_16x16x32_bf16(a0c, bq0, acc0, 0, 0, 0);
        acc1 = __builtin_amdgcn_mfma_f32_16x16x32_bf16(a1c, bq0, acc1, 0, 0, 0);
        a0c = a0n; a1c = a1n;
        bq0 = bq1; bq1 = bq2; bq2 = bq3; bq3 = bnew;
    }
    __builtin_amdgcn_s_setprio(0);

    // epilogue: acc IS h_prime (P pre-normalized) -> elu -> out
    const size_t ob = (size_t)(b * Nn) + i0;
    #pragma unroll
    for (int reg = 0; reg < 4; reg++) {
        float v;
        v = acc0[reg]; v = v > 0.f ? v : (__expf(v) - 1.f);
        out[(ob + quad * 4 + reg) * Ff + n0 + m] = v;
        v = acc1[reg]; v = v > 0.f ? v : (__expf(v) - 1.f);
        out[(ob + 16 + quad * 4 + reg) * Ff + n0 + m] = v;
    }
}

extern "C" void kernel_launch(void* const* d_in, const int* in_sizes, int n_in,
                              void* d_out, int out_size, void* d_ws, size_t ws_size,
                              hipStream_t stream)
{
    const void* h   = d_in[0];
    const void* adj = d_in[1];
    const void* W   = d_in[2];
    const void* a   = d_in[3];
    for (int i = 0; i < n_in; i++) {
        if      (in_sizes[i] == Bsz * Nn * Ff) h   = d_in[i];
        else if (in_sizes[i] == Bsz * Nn * Nn) adj = d_in[i];
        else if (in_sizes[i] == Ff * Ff)       W   = d_in[i];
        else if (in_sizes[i] == 2 * Ff)        a   = d_in[i];
    }
    float* out = (float*)d_out;

    char*  wsb = (char*)d_ws;
    float* w1  = (float*)wsb;                                   // 1 KiB
    float* w2  = w1 + Ff;                                       // 1 KiB
    float* f1  = (float*)(wsb + 4096);                          // 64 KiB
    float* f2  = f1 + Bsz * Nn;                                 // 64 KiB
    unsigned short* WhK = (unsigned short*)(wsb + 4096 + 2 * 65536);  // 8 MiB
    unsigned short* WK  = WhK + (size_t)Bsz * 32 * 8192;              // 128 KiB

    gat_prep<<<72, 256, 0, stream>>>((const float*)W, (const float*)a, w1, w2, WK);
    pack_f<<<512, 256, 0, stream>>>((const float*)h, WK, w1, w2, WhK, f1, f2);
    gat_attn<<<Bsz * (Nn / TI), 1024, 0, stream>>>((const int*)adj, f1, f2, WhK, out);
}